// Round 1
// baseline (149.624 us; speedup 1.0000x reference)
//
#include <hip/hip_runtime.h>
#include <hip/hip_bf16.h>

typedef __attribute__((ext_vector_type(8))) short bf16x8;
typedef __attribute__((ext_vector_type(4))) float f32x4;

#define NPIX 4096
#define NC   128

// ---------------- prep: build bf16 Kn[b][n][c], Q[b][n][c], Vt[b][c][n] ----------------
__global__ __launch_bounds__(256) void sffa_prep(
    const float* __restrict__ x, const float* __restrict__ mask,
    ushort* __restrict__ KnW, ushort* __restrict__ QW, ushort* __restrict__ VtW)
{
    __shared__ float xs[128][69];   // padded: phase-3 reads at ~4-way worst
    __shared__ float ms[64];
    __shared__ float rinv[64];
    __shared__ float part[4][64];
    const int tid = threadIdx.x;
    const int b = blockIdx.x >> 6, nblk = blockIdx.x & 63;
    const int n0 = nblk * 64;
    const float* xb = x + (size_t)b * NC * NPIX;

    #pragma unroll
    for (int it = 0; it < 8; ++it) {
        int e4 = it * 256 + tid;
        int c = e4 >> 4, n4 = (e4 & 15) * 4;
        float4 v = *(const float4*)(xb + (size_t)c * NPIX + n0 + n4);
        xs[c][n4+0] = v.x; xs[c][n4+1] = v.y; xs[c][n4+2] = v.z; xs[c][n4+3] = v.w;
    }
    if (tid < 16) {
        float4 mv = *(const float4*)(mask + (size_t)b * NPIX + n0 + tid * 4);
        ms[tid*4+0] = mv.x; ms[tid*4+1] = mv.y; ms[tid*4+2] = mv.z; ms[tid*4+3] = mv.w;
    }
    __syncthreads();
    {
        int p = tid & 63, qd = tid >> 6;
        float m = ms[p];
        float s = 0.f;
        #pragma unroll
        for (int i = 0; i < 32; ++i) {
            float k = fmaf(xs[qd*32 + i][p], m, 1e-7f);
            s = fmaf(k, k, s);
        }
        part[qd][p] = s;
    }
    __syncthreads();
    if (tid < 64) {
        float tot = part[0][tid] + part[1][tid] + part[2][tid] + part[3][tid];
        rinv[tid] = rsqrtf(tot);
    }
    __syncthreads();
    // Kn & Q, [n][c] bf16, coalesced ushort2 writes
    #pragma unroll
    for (int it = 0; it < 16; ++it) {
        int e2 = it * 256 + tid;
        int n = e2 >> 6, cp = (e2 & 63) * 2;
        float m = ms[n], r = rinv[n];
        float x0 = xs[cp][n], x1 = xs[cp+1][n];
        float k0 = fmaf(x0, m, 1e-7f), k1 = fmaf(x1, m, 1e-7f);
        size_t base = ((size_t)b * NPIX + n0 + n) * NC + cp;
        __hip_bfloat162 kn, q;
        kn.x = __float2bfloat16(k0 * r); kn.y = __float2bfloat16(k1 * r);
        q.x  = __float2bfloat16(x0);     q.y  = __float2bfloat16(x1);
        *(__hip_bfloat162*)(KnW + base) = kn;
        *(__hip_bfloat162*)(QW  + base) = q;
    }
    // Vt, [c][n] bf16 (same layout as source => coalesced)
    #pragma unroll
    for (int it = 0; it < 16; ++it) {
        int e2 = it * 256 + tid;
        int c = e2 >> 5, np = (e2 & 31) * 2;
        float k0 = fmaf(xs[c][np],   ms[np],   1e-7f);
        float k1 = fmaf(xs[c][np+1], ms[np+1], 1e-7f);
        __hip_bfloat162 v;
        v.x = __float2bfloat16(k0); v.y = __float2bfloat16(k1);
        *(__hip_bfloat162*)(VtW + ((size_t)b * NC + c) * NPIX + n0 + np) = v;
    }
}

// ---------------- flash attention + fused epilogue ----------------
#define SM_KN 0          // [64 keys][128 c] bf16, XOR-swizzled (16 KB); also Q staging; also epilogue agg
#define SM_VT 16384      // [128 c][128 slot] bf16 padded, XOR-swizzled (32 KB)
#define SM_P  49152      // 8 waves * 16 rows * 80 B = 10240
#define SM_ML 59392      // ma/la/mb/lb 4*64 floats = 1024
#define SM_SZ 60416

__global__ __launch_bounds__(512) void sffa_attn(
    const ushort* __restrict__ KnW, const ushort* __restrict__ QW,
    const ushort* __restrict__ VtW, const float* __restrict__ x,
    const float* __restrict__ mask, float* __restrict__ out)
{
    __shared__ __align__(16) char smem[SM_SZ];
    const int tid  = threadIdx.x;
    const int w    = tid >> 6, lane = tid & 63;
    const int l15  = lane & 15, g = lane >> 4;
    const int b    = blockIdx.x >> 6, qblk = blockIdx.x & 63;
    const int q0   = qblk * 64;
    const int half = w >> 2;   // key half (0: keys 0..31 of tile, 1: 32..63)
    const int wq   = w & 3;    // query strip: q0 + wq*16 + (frag col)

    const ushort* Knb = KnW + (size_t)b * NPIX * NC;
    const ushort* Qb  = QW  + (size_t)b * NPIX * NC + (size_t)q0 * NC;
    const ushort* Vtb = VtW + (size_t)b * NC * NPIX;

    // ---- stage Q tile (16 KB contiguous) into SM_KN with XOR swizzle ----
    #pragma unroll
    for (int it = 0; it < 2; ++it) {
        int L = (it * 512 + tid) * 16;
        int row = L >> 8, col = L & 255;
        int4 v = *(const int4*)((const char*)Qb + L);
        *(int4*)(smem + SM_KN + row * 256 + (col ^ ((row & 15) << 4))) = v;
    }
    __syncthreads();
    bf16x8 qf[4];   // B-operand frags: col=q (l15), k=c chunk
    {
        int qrow = wq * 16 + l15;
        #pragma unroll
        for (int kc = 0; kc < 4; ++kc)
            qf[kc] = *(const bf16x8*)(smem + SM_KN + qrow * 256 + ((64*kc + 16*g) ^ (l15 << 4)));
    }
    __syncthreads();

    f32x4 acc[8];
    const f32x4 fzero = {0.f, 0.f, 0.f, 0.f};
    #pragma unroll
    for (int i = 0; i < 8; ++i) acc[i] = fzero;
    float mrun = -1e30f, lrun = 0.f;
    char* Pw = smem + SM_P + w * 1280;   // 16 rows * 80 B

    for (int kt = 0; kt < 64; ++kt) {
        const int k0 = kt * 64;
        // stage Kn tile (contiguous 16 KB)
        #pragma unroll
        for (int it = 0; it < 2; ++it) {
            int L = (it * 512 + tid) * 16;
            int row = L >> 8, col = L & 255;
            int4 v = *(const int4*)((const char*)(Knb + (size_t)k0 * NC) + L);
            *(int4*)(smem + SM_KN + row * 256 + (col ^ ((row & 15) << 4))) = v;
        }
        // stage Vt tile: [c][8 slots of 8 keys]
        #pragma unroll
        for (int it = 0; it < 2; ++it) {
            int idx = it * 512 + tid;
            int c = idx >> 3, s = idx & 7;
            int4 v = *(const int4*)(Vtb + (size_t)c * NPIX + k0 + s * 8);
            *(int4*)(smem + SM_VT + c * 256 + ((s * 16) ^ ((c & 15) << 4))) = v;
        }
        __syncthreads();

        // S^T = Kn * Q : D[key(row), q(col)]; wave covers keys half*32 .. +32 (2 subtiles)
        f32x4 sa0 = fzero, sa1 = fzero;
        {
            const char* rb0 = smem + SM_KN + (half * 32 + l15) * 256;
            const char* rb1 = rb0 + 16 * 256;
            const int sw = l15 << 4;
            #pragma unroll
            for (int kc = 0; kc < 4; ++kc) {
                int off = (64 * kc + 16 * g) ^ sw;
                bf16x8 a0 = *(const bf16x8*)(rb0 + off);
                bf16x8 a1 = *(const bf16x8*)(rb1 + off);
                sa0 = __builtin_amdgcn_mfma_f32_16x16x32_bf16(a0, qf[kc], sa0, 0, 0, 0);
                sa1 = __builtin_amdgcn_mfma_f32_16x16x32_bf16(a1, qf[kc], sa1, 0, 0, 0);
            }
        }
        // online softmax; lane owns q=l15, 8 scores (keys 16t + 4g + r)
        float tmax = fmaxf(fmaxf(fmaxf(sa0[0], sa0[1]), fmaxf(sa0[2], sa0[3])),
                           fmaxf(fmaxf(sa1[0], sa1[1]), fmaxf(sa1[2], sa1[3])));
        tmax = fmaxf(tmax, __shfl_xor(tmax, 16));
        tmax = fmaxf(tmax, __shfl_xor(tmax, 32));
        float mnew = fmaxf(mrun, tmax);
        float sc = __expf(mrun - mnew);
        float p0[4], p1[4];
        float ts = 0.f;
        #pragma unroll
        for (int r = 0; r < 4; ++r) { p0[r] = __expf(sa0[r] - mnew); ts += p0[r]; }
        #pragma unroll
        for (int r = 0; r < 4; ++r) { p1[r] = __expf(sa1[r] - mnew); ts += p1[r]; }
        ts += __shfl_xor(ts, 16);
        ts += __shfl_xor(ts, 32);
        lrun = lrun * sc + ts;
        mrun = mnew;
        // rescale accumulator: acc rows are q = 4g + r -> fetch that q's factor
        float scr[4];
        #pragma unroll
        for (int r = 0; r < 4; ++r) scr[r] = __shfl(sc, 4 * g + r);
        #pragma unroll
        for (int ct = 0; ct < 8; ++ct) {
            acc[ct][0] *= scr[0]; acc[ct][1] *= scr[1];
            acc[ct][2] *= scr[2]; acc[ct][3] *= scr[3];
        }
        // pack P -> bf16 -> per-wave LDS strip ([q row l15][32 keys], stride 80 B)
        union { __hip_bfloat162 h; unsigned u; } ua0, ua1, ub0, ub1;
        ua0.h.x = __float2bfloat16(p0[0]); ua0.h.y = __float2bfloat16(p0[1]);
        ua1.h.x = __float2bfloat16(p0[2]); ua1.h.y = __float2bfloat16(p0[3]);
        ub0.h.x = __float2bfloat16(p1[0]); ub0.h.y = __float2bfloat16(p1[1]);
        ub1.h.x = __float2bfloat16(p1[2]); ub1.h.y = __float2bfloat16(p1[3]);
        *(int2*)(Pw + l15 * 80 +      8 * g) = make_int2((int)ua0.u, (int)ua1.u);
        *(int2*)(Pw + l15 * 80 + 32 + 8 * g) = make_int2((int)ub0.u, (int)ub1.u);
        // PV: A = P (row=q, k=key), B = V (k=key, col=c)
        bf16x8 pf = *(const bf16x8*)(Pw + l15 * 80 + 16 * g);
        #pragma unroll
        for (int ct = 0; ct < 8; ++ct) {
            int c = 16 * ct + l15;
            bf16x8 vf = *(const bf16x8*)(smem + SM_VT + c * 256 +
                                         ((64 * half + 16 * g) ^ ((c & 15) << 4)));
            acc[ct] = __builtin_amdgcn_mfma_f32_16x16x32_bf16(pf, vf, acc[ct], 0, 0, 0);
        }
        __syncthreads();
    }

    // ---- merge the two key-half partial softmax states, divide by l, write agg ----
    float* ma = (float*)(smem + SM_ML);
    float* la = ma + 64; float* mb = la + 64; float* lb = mb + 64;
    const int q = wq * 16 + l15;
    if (g == 0) {
        if (half == 0) { ma[q] = mrun; la[q] = lrun; }
        else           { mb[q] = mrun; lb[q] = lrun; }
    }
    __syncthreads();
    float* agg = (float*)smem;   // [128 c][68] fp32, reuses Kn/Vt space
    {
        float mstar = fmaxf(ma[q], mb[q]);
        float f = __expf(mrun - mstar);
        float fr[4];
        #pragma unroll
        for (int r = 0; r < 4; ++r) fr[r] = __shfl(f, 4 * g + r);
        if (half == 1) {
            #pragma unroll
            for (int ct = 0; ct < 8; ++ct) {
                int c = 16 * ct + l15;
                #pragma unroll
                for (int r = 0; r < 4; ++r)
                    agg[c * 68 + wq * 16 + 4 * g + r] = acc[ct][r] * fr[r];
            }
        }
        __syncthreads();
        if (half == 0) {
            float lstar = la[q] * __expf(ma[q] - mstar) + lb[q] * __expf(mb[q] - mstar);
            float linv = 1.f / lstar;
            float li[4];
            #pragma unroll
            for (int r = 0; r < 4; ++r) li[r] = __shfl(linv, 4 * g + r);
            #pragma unroll
            for (int ct = 0; ct < 8; ++ct) {
                int c = 16 * ct + l15;
                #pragma unroll
                for (int r = 0; r < 4; ++r) {
                    int idx = c * 68 + wq * 16 + 4 * g + r;
                    agg[idx] = (acc[ct][r] * fr[r] + agg[idx]) * li[r];
                }
            }
        }
    }
    __syncthreads();
    // ---- fused select + coalesced store: out = mask ? x : agg ----
    const float* xb  = x    + (size_t)b * NC * NPIX;
    const float* mkb = mask + (size_t)b * NPIX;
    float* ob        = out  + (size_t)b * NC * NPIX;
    #pragma unroll
    for (int it = 0; it < 4; ++it) {
        int e4 = it * 512 + tid;
        int c = e4 >> 4, n4 = (e4 & 15) * 4;
        float4 xi = *(const float4*)(xb + (size_t)c * NPIX + q0 + n4);
        float4 mk = *(const float4*)(mkb + q0 + n4);
        float4 av = *(const float4*)(agg + c * 68 + n4);
        float4 o;
        o.x = mk.x > 0.5f ? xi.x : av.x;
        o.y = mk.y > 0.5f ? xi.y : av.y;
        o.z = mk.z > 0.5f ? xi.z : av.z;
        o.w = mk.w > 0.5f ? xi.w : av.w;
        *(float4*)(ob + (size_t)c * NPIX + q0 + n4) = o;
    }
}

extern "C" void kernel_launch(void* const* d_in, const int* in_sizes, int n_in,
                              void* d_out, int out_size, void* d_ws, size_t ws_size,
                              hipStream_t stream) {
    const float* x    = (const float*)d_in[0];
    const float* mask = (const float*)d_in[1];
    ushort* KnW = (ushort*)d_ws;                       // 4*4096*128 bf16 = 4 MB
    ushort* QW  = KnW + (size_t)4 * NPIX * NC;         // 4 MB
    ushort* VtW = QW  + (size_t)4 * NPIX * NC;         // 4 MB
    sffa_prep<<<256, 256, 0, stream>>>(x, mask, KnW, QW, VtW);
    sffa_attn<<<256, 512, 0, stream>>>(KnW, QW, VtW, x, mask, (float*)d_out);
}

// Round 2
// 72.256 us; speedup vs baseline: 2.0708x; 2.0708x over previous
//
#include <hip/hip_runtime.h>
#include <hip/hip_bf16.h>

typedef __attribute__((ext_vector_type(8))) short bf16x8;
typedef __attribute__((ext_vector_type(4))) float f32x4;

#define NPIX 4096
#define NC   128
#define KSPLIT 2
#define KCHUNK (NPIX / KSPLIT)
#define NTK (KCHUNK / 64)

// ---------------- prep: build bf16 Kn[b][n][c], Q[b][n][c], Vt[b][c][n] ----------------
__global__ __launch_bounds__(256) void sffa_prep(
    const float* __restrict__ x, const float* __restrict__ mask,
    ushort* __restrict__ KnW, ushort* __restrict__ QW, ushort* __restrict__ VtW)
{
    __shared__ float xs[128][69];
    __shared__ float ms[64];
    __shared__ float rinv[64];
    __shared__ float part[4][64];
    const int tid = threadIdx.x;
    const int b = blockIdx.x >> 6, nblk = blockIdx.x & 63;
    const int n0 = nblk * 64;
    const float* xb = x + (size_t)b * NC * NPIX;

    #pragma unroll
    for (int it = 0; it < 8; ++it) {
        int e4 = it * 256 + tid;
        int c = e4 >> 4, n4 = (e4 & 15) * 4;
        float4 v = *(const float4*)(xb + (size_t)c * NPIX + n0 + n4);
        xs[c][n4+0] = v.x; xs[c][n4+1] = v.y; xs[c][n4+2] = v.z; xs[c][n4+3] = v.w;
    }
    if (tid < 16) {
        float4 mv = *(const float4*)(mask + (size_t)b * NPIX + n0 + tid * 4);
        ms[tid*4+0] = mv.x; ms[tid*4+1] = mv.y; ms[tid*4+2] = mv.z; ms[tid*4+3] = mv.w;
    }
    __syncthreads();
    {
        int p = tid & 63, qd = tid >> 6;
        float m = ms[p];
        float s = 0.f;
        #pragma unroll
        for (int i = 0; i < 32; ++i) {
            float k = fmaf(xs[qd*32 + i][p], m, 1e-7f);
            s = fmaf(k, k, s);
        }
        part[qd][p] = s;
    }
    __syncthreads();
    if (tid < 64) {
        float tot = part[0][tid] + part[1][tid] + part[2][tid] + part[3][tid];
        rinv[tid] = rsqrtf(tot);
    }
    __syncthreads();
    #pragma unroll
    for (int it = 0; it < 16; ++it) {
        int e2 = it * 256 + tid;
        int n = e2 >> 6, cp = (e2 & 63) * 2;
        float m = ms[n], r = rinv[n];
        float x0 = xs[cp][n], x1 = xs[cp+1][n];
        float k0 = fmaf(x0, m, 1e-7f), k1 = fmaf(x1, m, 1e-7f);
        size_t base = ((size_t)b * NPIX + n0 + n) * NC + cp;
        __hip_bfloat162 kn, q;
        kn.x = __float2bfloat16(k0 * r); kn.y = __float2bfloat16(k1 * r);
        q.x  = __float2bfloat16(x0);     q.y  = __float2bfloat16(x1);
        *(__hip_bfloat162*)(KnW + base) = kn;
        *(__hip_bfloat162*)(QW  + base) = q;
    }
    #pragma unroll
    for (int it = 0; it < 16; ++it) {
        int e2 = it * 256 + tid;
        int c = e2 >> 5, np = (e2 & 31) * 2;
        float k0 = fmaf(xs[c][np],   ms[np],   1e-7f);
        float k1 = fmaf(xs[c][np+1], ms[np+1], 1e-7f);
        __hip_bfloat162 v;
        v.x = __float2bfloat16(k0); v.y = __float2bfloat16(k1);
        *(__hip_bfloat162*)(VtW + ((size_t)b * NC + c) * NPIX + n0 + np) = v;
    }
}

// ---------------- flash attention, key-split, partial outputs ----------------
// LDS map: buf0 {Kn 16K @0, Vt 16K @16384}, buf1 @32768, P @65536 (10240), ML @75776
#define L_BUF 32768
#define L_P   65536
#define L_ML  75776
#define L_SZ  76800

__global__ __launch_bounds__(512, 4) void sffa_attn(
    const ushort* __restrict__ KnW, const ushort* __restrict__ QW,
    const ushort* __restrict__ VtW,
    ushort* __restrict__ partW, float* __restrict__ mlW)
{
    __shared__ __align__(16) char smem[L_SZ];
    const int tid  = threadIdx.x;
    const int w = tid >> 6, lane = tid & 63;
    const int l15 = lane & 15, g = lane >> 4;
    // XCD-aware bijective swizzle (512 = 8 * 64)
    const int bx = ((int)blockIdx.x & 7) * 64 + ((int)blockIdx.x >> 3);
    const int b = bx >> 7, qblk = (bx >> 1) & 63, ks = bx & 1;
    const int q0 = qblk * 64;
    const int kbase = ks * KCHUNK;
    const int half = w >> 2;   // key half of the 64-key tile
    const int wq   = w & 3;    // query strip

    const ushort* Knb = KnW + (size_t)b * NPIX * NC;
    const ushort* Qb  = QW  + (size_t)b * NPIX * NC + (size_t)q0 * NC;
    const ushort* Vtb = VtW + (size_t)b * NC * NPIX;

    // ---- stage Q tile into buf0 region, read q-fragments ----
    #pragma unroll
    for (int it = 0; it < 2; ++it) {
        int L = (it * 512 + tid) * 16;
        int row = L >> 8, col = L & 255;
        int4 v = *(const int4*)((const char*)Qb + L);
        *(int4*)(smem + row * 256 + (col ^ ((row & 15) << 4))) = v;
    }
    __syncthreads();
    bf16x8 qf[4];
    {
        int qrow = wq * 16 + l15;
        #pragma unroll
        for (int kc = 0; kc < 4; ++kc)
            qf[kc] = *(const bf16x8*)(smem + qrow * 256 + ((64*kc + 16*g) ^ (l15 << 4)));
    }
    __syncthreads();

    // staging address precompute
    const int kOff = (tid >> 4) * 256 + (((tid & 15) * 16) ^ (((tid >> 4) & 15) << 4));
    const int cV = tid >> 3, sV = tid & 7;
    const int vOff = cV * 128 + ((sV * 16) ^ ((cV & 7) << 4));
    const int4* kgbase = (const int4*)(Knb + (size_t)kbase * NC);
    const ushort* vgbase = Vtb + (size_t)cV * NPIX + kbase + sV * 8;

    int4 pr0, pr1, pr2, pr3;
    // tile 0 -> buf0
    pr0 = kgbase[tid]; pr1 = kgbase[512 + tid];
    pr2 = *(const int4*)(vgbase);
    pr3 = *(const int4*)(vgbase + (size_t)64 * NPIX);
    {
        char* base = smem;
        *(int4*)(base + kOff) = pr0;
        *(int4*)(base + kOff + 8192) = pr1;
        *(int4*)(base + 16384 + vOff) = pr2;
        *(int4*)(base + 16384 + vOff + 8192) = pr3;
    }
    // tile 1 -> regs
    pr0 = kgbase[1024 + tid]; pr1 = kgbase[1536 + tid];
    pr2 = *(const int4*)(vgbase + 64);
    pr3 = *(const int4*)(vgbase + (size_t)64 * NPIX + 64);
    __syncthreads();

    f32x4 acc[8];
    const f32x4 fzero = {0.f, 0.f, 0.f, 0.f};
    #pragma unroll
    for (int i = 0; i < 8; ++i) acc[i] = fzero;
    float mrun = -1e30f, lrun = 0.f;
    char* Pw = smem + L_P + w * 1280;

    for (int kt = 0; kt < NTK; ++kt) {
        // write tile kt+1 from regs (compiler inserts vmcnt wait)
        if (kt + 1 < NTK) {
            char* base = smem + ((kt + 1) & 1) * L_BUF;
            *(int4*)(base + kOff) = pr0;
            *(int4*)(base + kOff + 8192) = pr1;
            *(int4*)(base + 16384 + vOff) = pr2;
            *(int4*)(base + 16384 + vOff + 8192) = pr3;
        }
        // issue loads for tile kt+2 (in flight across compute)
        if (kt + 2 < NTK) {
            pr0 = kgbase[(kt + 2) * 1024 + tid];
            pr1 = kgbase[(kt + 2) * 1024 + 512 + tid];
            pr2 = *(const int4*)(vgbase + (kt + 2) * 64);
            pr3 = *(const int4*)(vgbase + (size_t)64 * NPIX + (kt + 2) * 64);
        }
        // ---- compute tile kt from buf[kt&1] ----
        char* bb = smem + (kt & 1) * L_BUF;
        f32x4 sa0 = fzero, sa1 = fzero;
        {
            const char* rb0 = bb + (half * 32 + l15) * 256;
            const char* rb1 = rb0 + 4096;
            const int sw = l15 << 4;
            __builtin_amdgcn_s_setprio(1);
            #pragma unroll
            for (int kc = 0; kc < 4; ++kc) {
                int off = (64 * kc + 16 * g) ^ sw;
                bf16x8 a0 = *(const bf16x8*)(rb0 + off);
                bf16x8 a1 = *(const bf16x8*)(rb1 + off);
                sa0 = __builtin_amdgcn_mfma_f32_16x16x32_bf16(a0, qf[kc], sa0, 0, 0, 0);
                sa1 = __builtin_amdgcn_mfma_f32_16x16x32_bf16(a1, qf[kc], sa1, 0, 0, 0);
            }
            __builtin_amdgcn_s_setprio(0);
        }
        // online softmax with defer-max (THR=8)
        float tmax = fmaxf(fmaxf(fmaxf(sa0[0], sa0[1]), fmaxf(sa0[2], sa0[3])),
                           fmaxf(fmaxf(sa1[0], sa1[1]), fmaxf(sa1[2], sa1[3])));
        tmax = fmaxf(tmax, __shfl_xor(tmax, 16));
        tmax = fmaxf(tmax, __shfl_xor(tmax, 32));
        bool grow = !__all(tmax <= mrun + 8.f);
        float mnew = grow ? fmaxf(mrun, tmax) : mrun;
        float p0[4], p1[4];
        float ts = 0.f;
        #pragma unroll
        for (int r = 0; r < 4; ++r) { p0[r] = __expf(sa0[r] - mnew); ts += p0[r]; }
        #pragma unroll
        for (int r = 0; r < 4; ++r) { p1[r] = __expf(sa1[r] - mnew); ts += p1[r]; }
        ts += __shfl_xor(ts, 16);
        ts += __shfl_xor(ts, 32);
        if (grow) {
            float sc = __expf(mrun - mnew);
            lrun = lrun * sc + ts;
            float scr[4];
            #pragma unroll
            for (int r = 0; r < 4; ++r) scr[r] = __shfl(sc, 4 * g + r);
            #pragma unroll
            for (int ct = 0; ct < 8; ++ct) {
                acc[ct][0] *= scr[0]; acc[ct][1] *= scr[1];
                acc[ct][2] *= scr[2]; acc[ct][3] *= scr[3];
            }
            mrun = mnew;
        } else {
            lrun += ts;
        }
        // pack P -> bf16 -> per-wave LDS strip
        union { __hip_bfloat162 h; unsigned u; } ua0, ua1, ub0, ub1;
        ua0.h.x = __float2bfloat16(p0[0]); ua0.h.y = __float2bfloat16(p0[1]);
        ua1.h.x = __float2bfloat16(p0[2]); ua1.h.y = __float2bfloat16(p0[3]);
        ub0.h.x = __float2bfloat16(p1[0]); ub0.h.y = __float2bfloat16(p1[1]);
        ub1.h.x = __float2bfloat16(p1[2]); ub1.h.y = __float2bfloat16(p1[3]);
        *(int2*)(Pw + l15 * 80 +      8 * g) = make_int2((int)ua0.u, (int)ua1.u);
        *(int2*)(Pw + l15 * 80 + 32 + 8 * g) = make_int2((int)ub0.u, (int)ub1.u);
        // PV
        bf16x8 pf = *(const bf16x8*)(Pw + l15 * 80 + 16 * g);
        {
            const char* vb = bb + 16384;
            __builtin_amdgcn_s_setprio(1);
            #pragma unroll
            for (int ct = 0; ct < 8; ++ct) {
                int c = 16 * ct + l15;
                bf16x8 vf = *(const bf16x8*)(vb + c * 128 +
                                             ((64 * half + 16 * g) ^ ((c & 7) << 4)));
                acc[ct] = __builtin_amdgcn_mfma_f32_16x16x32_bf16(pf, vf, acc[ct], 0, 0, 0);
            }
            __builtin_amdgcn_s_setprio(0);
        }
        __syncthreads();
    }

    // ---- merge two key-half partial states in-block; write UNNORMALIZED partial ----
    float* ma = (float*)(smem + L_ML);
    float* la = ma + 64; float* mb = la + 64; float* lb = mb + 64;
    const int q = wq * 16 + l15;
    if (g == 0) {
        if (half == 0) { ma[q] = mrun; la[q] = lrun; }
        else           { mb[q] = mrun; lb[q] = lrun; }
    }
    __syncthreads();
    float* agg = (float*)smem;   // [128 c][68] fp32 (34816 B, reuses tile buffers)
    {
        float mstar = fmaxf(ma[q], mb[q]);
        float f = __expf(mrun - mstar);
        float fr[4];
        #pragma unroll
        for (int r = 0; r < 4; ++r) fr[r] = __shfl(f, 4 * g + r);
        if (half == 1) {
            #pragma unroll
            for (int ct = 0; ct < 8; ++ct) {
                int c = 16 * ct + l15;
                #pragma unroll
                for (int r = 0; r < 4; ++r)
                    agg[c * 68 + wq * 16 + 4 * g + r] = acc[ct][r] * fr[r];
            }
        }
        __syncthreads();
        if (half == 0) {
            #pragma unroll
            for (int ct = 0; ct < 8; ++ct) {
                int c = 16 * ct + l15;
                #pragma unroll
                for (int r = 0; r < 4; ++r) {
                    int idx = c * 68 + wq * 16 + 4 * g + r;
                    agg[idx] = acc[ct][r] * fr[r] + agg[idx];
                }
            }
        }
    }
    __syncthreads();
    if (tid < 64) {
        float M = fmaxf(ma[tid], mb[tid]);
        float ls = la[tid] * __expf(ma[tid] - M) + lb[tid] * __expf(mb[tid] - M);
        *(float2*)(mlW + ((size_t)bx * 64 + tid) * 2) = make_float2(M, ls);
    }
    ushort* pdst = partW + (size_t)bx * 8192;
    #pragma unroll
    for (int it = 0; it < 8; ++it) {
        int idx = it * 512 + tid;
        int c = idx >> 5, n2 = (idx & 31) * 2;
        __hip_bfloat162 h;
        h.x = __float2bfloat16(agg[c * 68 + n2]);
        h.y = __float2bfloat16(agg[c * 68 + n2 + 1]);
        *(__hip_bfloat162*)(pdst + c * 64 + n2) = h;
    }
}

// ---------------- merge key-split partials + fused mask-select epilogue ----------------
__global__ __launch_bounds__(256) void sffa_merge(
    const ushort* __restrict__ partW, const float* __restrict__ mlW,
    const float* __restrict__ x, const float* __restrict__ mask,
    float* __restrict__ out)
{
    __shared__ float g0s[64], g1s[64];
    const int tid = threadIdx.x;
    const int m = blockIdx.x, b = m >> 6, qblk = m & 63, q0 = qblk * 64;
    const int bx0 = m * 2;
    if (tid < 64) {
        float2 ml0 = *(const float2*)(mlW + ((size_t)bx0 * 64 + tid) * 2);
        float2 ml1 = *(const float2*)(mlW + ((size_t)(bx0 + 1) * 64 + tid) * 2);
        float M = fmaxf(ml0.x, ml1.x);
        float f0 = __expf(ml0.x - M), f1 = __expf(ml1.x - M);
        float L = ml0.y * f0 + ml1.y * f1;
        g0s[tid] = f0 / L; g1s[tid] = f1 / L;
    }
    __syncthreads();
    const ushort* p0 = partW + (size_t)bx0 * 8192;
    const ushort* p1 = p0 + 8192;
    const float* xb  = x    + (size_t)b * NC * NPIX;
    const float* mkb = mask + (size_t)b * NPIX;
    float* ob        = out  + (size_t)b * NC * NPIX;
    #pragma unroll
    for (int it = 0; it < 8; ++it) {
        int idx = it * 256 + tid;
        int c = idx >> 4, n4 = (idx & 15) * 4;
        uint2 a = *(const uint2*)(p0 + c * 64 + n4);
        uint2 bb = *(const uint2*)(p1 + c * 64 + n4);
        float4 xi = *(const float4*)(xb + (size_t)c * NPIX + q0 + n4);
        float4 mk = *(const float4*)(mkb + q0 + n4);
        float a0 = __uint_as_float((a.x & 0xffffu) << 16);
        float a1 = __uint_as_float((a.x >> 16) << 16);
        float a2 = __uint_as_float((a.y & 0xffffu) << 16);
        float a3 = __uint_as_float((a.y >> 16) << 16);
        float b0 = __uint_as_float((bb.x & 0xffffu) << 16);
        float b1 = __uint_as_float((bb.x >> 16) << 16);
        float b2 = __uint_as_float((bb.y & 0xffffu) << 16);
        float b3 = __uint_as_float((bb.y >> 16) << 16);
        float4 o;
        o.x = mk.x > 0.5f ? xi.x : (a0 * g0s[n4 + 0] + b0 * g1s[n4 + 0]);
        o.y = mk.y > 0.5f ? xi.y : (a1 * g0s[n4 + 1] + b1 * g1s[n4 + 1]);
        o.z = mk.z > 0.5f ? xi.z : (a2 * g0s[n4 + 2] + b2 * g1s[n4 + 2]);
        o.w = mk.w > 0.5f ? xi.w : (a3 * g0s[n4 + 3] + b3 * g1s[n4 + 3]);
        *(float4*)(ob + (size_t)c * NPIX + q0 + n4) = o;
    }
}

extern "C" void kernel_launch(void* const* d_in, const int* in_sizes, int n_in,
                              void* d_out, int out_size, void* d_ws, size_t ws_size,
                              hipStream_t stream) {
    const float* x    = (const float*)d_in[0];
    const float* mask = (const float*)d_in[1];
    char* ws = (char*)d_ws;
    ushort* KnW  = (ushort*)ws;                                  // 4 MB
    ushort* QW   = (ushort*)(ws + (size_t)4 * 1024 * 1024);      // 4 MB
    ushort* VtW  = (ushort*)(ws + (size_t)8 * 1024 * 1024);      // 4 MB
    ushort* part = (ushort*)(ws + (size_t)12 * 1024 * 1024);     // 512*8192*2 = 8 MB
    float*  mlW  = (float*)(ws + (size_t)21 * 1024 * 1024);      // 512*64*2*4 = 256 KB
    sffa_prep<<<256, 256, 0, stream>>>(x, mask, KnW, QW, VtW);
    sffa_attn<<<512, 512, 0, stream>>>(KnW, QW, VtW, part, mlW);
    sffa_merge<<<256, 256, 0, stream>>>(part, mlW, x, mask, (float*)d_out);
}